// Round 1
// baseline (14768.822 us; speedup 1.0000x reference)
//
#include <hip/hip_runtime.h>
#include <cstdint>
#include <cstddef>

#define LI 64
#define LO 64
#define NB 32
#define E  128
#define ENC 128
#define D2 128
#define VOC 32000
#define CIN 384   // 2*ENC + E
#define G5 640    // 5*D2
#define G4 512    // 4*ENC
#define NCK 256   // vocab chunks
#define VPC 125   // vocab per chunk

__device__ __forceinline__ float sigf(float x) { return 1.0f / (1.0f + __expf(-x)); }
__device__ __forceinline__ float tanhf_(float x) {
  float e = __expf(2.0f * x);
  return 1.0f - 2.0f / (e + 1.0f);
}

// broadcast lane l of v to all lanes via SGPR (v_readlane_b32)
__device__ __forceinline__ float rl(float v, int l) {
  return __int_as_float(__builtin_amdgcn_readlane(__float_as_int(v), l));
}

// raw barrier: wait LDS only (lgkmcnt), do NOT drain vmcnt (global stores /
// prefetches stay in flight across the barrier; kernel-end flush covers them)
#define BARL() __asm__ __volatile__("s_waitcnt lgkmcnt(0)\n\ts_barrier" ::: "memory")

// ---------------------------------------------------------------------------
// K1: embedding gather + encoder input precompute  Xf/Xb = emb@Wih.T + bih+bhh
// grid 256 = 64 t * 4 bgroups(8), block 512
__global__ __launch_bounds__(512) void k_embed_encpre(
    const int* __restrict__ x, const float* __restrict__ embed,
    const float* __restrict__ Wf, const float* __restrict__ bihf, const float* __restrict__ bhhf,
    const float* __restrict__ Wb, const float* __restrict__ bihb, const float* __restrict__ bhhb,
    float* __restrict__ Xf, float* __restrict__ Xb)
{
  int t = blockIdx.x >> 2, bg = (blockIdx.x & 3) * 8;
  __shared__ float4 embs[8][E/4];
  int tid = threadIdx.x;
  for (int idx = tid; idx < 8 * E; idx += 512) {
    int bb = idx >> 7, e = idx & 127;
    int tok = x[t * NB + bg + bb];
    ((float*)embs[bb])[e] = embed[(size_t)tok * E + e];
  }
  __syncthreads();
  int gd = tid;
  for (int dir = 0; dir < 2; ++dir) {
    const float4* wrow = (const float4*)((dir ? Wb : Wf) + (size_t)gd * E);
    float bias = dir ? (bihb[gd] + bhhb[gd]) : (bihf[gd] + bhhf[gd]);
    float acc[8];
    #pragma unroll
    for (int r = 0; r < 8; ++r) acc[r] = bias;
    for (int q = 0; q < E/4; ++q) {
      float4 w = wrow[q];
      #pragma unroll
      for (int r = 0; r < 8; ++r) {
        float4 e4 = embs[r][q];
        acc[r] += w.x*e4.x + w.y*e4.y + w.z*e4.z + w.w*e4.w;
      }
    }
    float* X = dir ? Xb : Xf;
    #pragma unroll
    for (int r = 0; r < 8; ++r)
      X[(size_t)(t * NB + bg + r) * G4 + gd] = acc[r];
  }
}

// ---------------------------------------------------------------------------
// K2: bidirectional encoder LSTM. grid 64 = 32 b * 2 dir, block 512.
// torch gate order (i,f,g,o).
__global__ __launch_bounds__(512) void k_encoder(
    const float* __restrict__ Xf, const float* __restrict__ Xb,
    const float* __restrict__ Whhf, const float* __restrict__ Whhb,
    float* __restrict__ henc)
{
  int b = blockIdx.x >> 1, dir = blockIdx.x & 1;
  const float* X   = dir ? Xb   : Xf;
  const float* Whh = dir ? Whhb : Whhf;
  int tid = threadIdx.x;
  float4 w[ENC/4];
  {
    const float4* wrow = (const float4*)(Whh + (size_t)tid * ENC);
    #pragma unroll
    for (int q = 0; q < ENC/4; ++q) w[q] = wrow[q];
  }
  __shared__ float4 hb4[ENC/4];
  __shared__ float zb[G4];
  if (tid < ENC/4) hb4[tid] = make_float4(0.f, 0.f, 0.f, 0.f);
  float c = 0.0f;
  __syncthreads();
  for (int st = 0; st < LI; ++st) {
    int t = dir ? (LI - 1 - st) : st;
    float acc = X[(size_t)(t * NB + b) * G4 + tid];
    #pragma unroll
    for (int q = 0; q < ENC/4; ++q) {
      float4 h4 = hb4[q];
      float4 ww = w[q];
      acc += ww.x*h4.x + ww.y*h4.y + ww.z*h4.z + ww.w*h4.w;
    }
    zb[tid] = acc;
    __syncthreads();
    if (tid < ENC) {
      float zi = zb[tid], zf = zb[ENC + tid], zg = zb[2*ENC + tid], zo = zb[3*ENC + tid];
      c = sigf(zf) * c + sigf(zi) * tanhf_(zg);
      float h = sigf(zo) * tanhf_(c);
      ((float*)hb4)[tid] = h;
      henc[(size_t)(t * NB + b) * (2*ENC) + dir*ENC + tid] = h;
    }
    __syncthreads();
  }
}

// ---------------------------------------------------------------------------
// K3: Hx = henc @ Wx[:,128:384].T + bx + bs ; also seeds Vpre[0] (row 0: s_ver=0)
// grid 256 (8 rows each of 2048), block 640
__global__ __launch_bounds__(640) void k_hx(
    const float* __restrict__ henc, const float* __restrict__ Wx,
    const float* __restrict__ bx, const float* __restrict__ bs,
    float* __restrict__ Hx, float* __restrict__ Vpre0)
{
  int rowbase = blockIdx.x * 8;
  __shared__ float4 hh[8][(2*ENC)/4];
  int tid = threadIdx.x;
  for (int idx = tid; idx < 8 * 2 * ENC; idx += 640) {
    int rr = idx >> 8, k = idx & 255;
    ((float*)hh[rr])[k] = henc[(size_t)(rowbase + rr) * (2*ENC) + k];
  }
  __syncthreads();
  int gd = tid;
  const float4* wrow = (const float4*)(Wx + (size_t)gd * CIN + E);
  float bias = bx[gd] + bs[gd];
  float acc[8];
  #pragma unroll
  for (int r = 0; r < 8; ++r) acc[r] = bias;
  for (int q = 0; q < (2*ENC)/4; ++q) {
    float4 w = wrow[q];
    #pragma unroll
    for (int r = 0; r < 8; ++r) {
      float4 h4 = hh[r][q];
      acc[r] += w.x*h4.x + w.y*h4.y + w.z*h4.z + w.w*h4.w;
    }
  }
  #pragma unroll
  for (int r = 0; r < 8; ++r) {
    size_t o = (size_t)(rowbase + r) * G5 + gd;
    Hx[o] = acc[r];
    Vpre0[o] = acc[r];
  }
}

// ---------------------------------------------------------------------------
// K4 (per row): argmax(prev logits) -> y -> Yx, then 64 sequential 2D-LSTM cells.
// grid 32 (one WG per batch element), block 640 = 10 waves (3/3/2/2 per SIMD).
//
// __launch_bounds__(640, 3): cap VGPRs at 512/3 = 170 so the 128-float Ws row
// stays register-resident (previous build: VGPR_Count=80 < 128 => weights were
// re-fetched from L2 every step).
//
// s-broadcast: each wave holds s as 2 per-lane regs (s_lo = s[lane],
// s_hi = s[64+lane]); the 128-dot runs as readlane(SGPR)+v_fmac, eliminating
// the 32 uniform ds_read_b128 per wave per step.
//
// Gate phase on threads [128,256) (waves 2,3 -> the 2-wave SIMDs) to balance
// VALU issue against the 3-wave SIMDs.
__global__ __launch_bounds__(640, 3) void k_row(
    int row,
    const float* __restrict__ embed, const float* __restrict__ Wx,
    const float* __restrict__ Ws,
    const float* __restrict__ Vpre,   // Vpre[row&1]: Hx + s_ver part + biases
    const float* __restrict__ cprev,  // c_row of previous row
    float* __restrict__ scur, float* __restrict__ ccur,
    const float* __restrict__ ckval, const int* __restrict__ ckidx)
{
  int b = blockIdx.x, tid = threadIdx.x;
  int lane = tid & 63;
  __shared__ float zb[G5];
  __shared__ float sbuf[D2];
  __shared__ float ybuf[E];
  __shared__ int tokls;
  float yxr = 0.0f;
  if (row > 0) {
    if (tid < 64) {
      float bv = -3.4e38f; int bi = 0x7fffffff;
      #pragma unroll
      for (int cc = 0; cc < 4; ++cc) {
        int c = tid + 64 * cc;
        float v = ckval[b * NCK + c];
        int   id = ckidx[b * NCK + c];
        if (v > bv || (v == bv && id < bi)) { bv = v; bi = id; }
      }
      #pragma unroll
      for (int off = 1; off < 64; off <<= 1) {
        float ov = __shfl_xor(bv, off);
        int   oi = __shfl_xor(bi, off);
        if (ov > bv || (ov == bv && oi < bi)) { bv = ov; bi = oi; }
      }
      if (tid == 0) tokls = bi;
    }
    __syncthreads();
    int tok = tokls;
    if (tid < E) ybuf[tid] = embed[(size_t)tok * E + tid];
    __syncthreads();
    const float4* wy = (const float4*)(Wx + (size_t)tid * CIN);
    const float4* y4 = (const float4*)ybuf;
    float a = 0.0f;
    #pragma unroll
    for (int q = 0; q < E/4; ++q) {
      float4 w = wy[q], y = y4[q];
      a += w.x*y.x + w.y*y.y + w.z*y.z + w.w*y.w;
    }
    yxr = a;
  }
  // recurrent weights Ws[:,0:128] -> 128 VGPRs (must stay resident!)
  float4 w4[D2/4];
  {
    const float4* wrow = (const float4*)(Ws + (size_t)tid * (2*D2));
    #pragma unroll
    for (int q = 0; q < D2/4; ++q) w4[q] = wrow[q];
  }
  const float* wk = (const float*)w4;

  int gate = (tid >= D2 && tid < 2*D2);
  int d = tid - D2;
  float chor = 0.0f;
  float s_lo = 0.0f, s_hi = 0.0f;
  float vnext = Vpre[(size_t)(0 * NB + b) * G5 + tid];
  float cvn = gate ? cprev[(size_t)(0 * NB + b) * D2 + d] : 0.0f;
  __syncthreads();

  for (int j = 0; j < LI; ++j) {
    float acc = yxr + vnext;
    if (j < LI - 1) vnext = Vpre[(size_t)((j + 1) * NB + b) * G5 + tid];
    // z[tid] = yx + v + Ws_h[tid,:] . s   (s broadcast via SGPR readlane;
    // single accumulator, ascending k => same fma-chain order as before)
    #pragma unroll
    for (int k = 0; k < 64; ++k) acc = fmaf(rl(s_lo, k), wk[k], acc);
    #pragma unroll
    for (int k = 0; k < 64; ++k) acc = fmaf(rl(s_hi, k), wk[64 + k], acc);
    zb[tid] = acc;
    BARL();
    if (gate) {
      float zi = zb[d], zf = zb[D2 + d], zo = zb[2*D2 + d],
            zl = zb[3*D2 + d], zg = zb[4*D2 + d];
      float cv = cvn;
      if (j < LI - 1) cvn = cprev[(size_t)((j + 1) * NB + b) * D2 + d];
      float ii = sigf(zi), ff = sigf(zf), oo = sigf(zo), ll = sigf(zl);
      float gg = tanhf_(zg);
      float c = ff * (ll * chor + (1.0f - ll) * cv) + ii * gg;
      float s = oo * tanhf_(c);
      chor = c;
      sbuf[d] = s;
      size_t o = (size_t)(j * NB + b) * D2 + d;
      ccur[o] = c;
      scur[o] = s;
    }
    BARL();
    s_lo = sbuf[lane];
    s_hi = sbuf[64 + lane];
  }
}

// ---------------------------------------------------------------------------
// K5 (per row i, launched for i=0..64): three parts by blockIdx.
//  [0,256):  logits of row i (chunked) + per-chunk max/argmax
//  [256,512): Vpre[(i+1)&1] = Hx + s_row_i @ Ws[:,128:256].T
//  [512,544): softmax finalize + probs write of row i-1
__global__ __launch_bounds__(256) void k_fused(
    int row,
    const float* __restrict__ scur,
    const float* __restrict__ logW, const float* __restrict__ logb,
    const float* __restrict__ Ws, const float* __restrict__ Hx,
    float* __restrict__ Vnxt,
    float* __restrict__ lgcur, float* __restrict__ ckvalcur, int* __restrict__ ckidxcur,
    const float* __restrict__ lgprev, const float* __restrict__ ckvalprev,
    float* __restrict__ dout)
{
  int bid = blockIdx.x, tid = threadIdx.x;
  if (bid < 256) {
    if (row >= 64) return;
    int b = tid >> 3, r = tid & 7;
    const float4* sp = (const float4*)(scur + (size_t)(63 * NB + b) * D2 + r * 16);
    float4 s0 = sp[0], s1 = sp[1], s2 = sp[2], s3 = sp[3];
    float bm = -3.4e38f; int bmi = 0;
    int v0 = bid * VPC;
    for (int k = 0; k < VPC; ++k) {
      int v = v0 + k;
      const float4* lw = (const float4*)(logW + (size_t)v * D2 + r * 16);
      float4 a0 = lw[0], a1 = lw[1], a2 = lw[2], a3 = lw[3];
      float sum = a0.x*s0.x + a0.y*s0.y + a0.z*s0.z + a0.w*s0.w
                + a1.x*s1.x + a1.y*s1.y + a1.z*s1.z + a1.w*s1.w
                + a2.x*s2.x + a2.y*s2.y + a2.z*s2.z + a2.w*s2.w
                + a3.x*s3.x + a3.y*s3.y + a3.z*s3.z + a3.w*s3.w;
      sum += __shfl_xor(sum, 1);
      sum += __shfl_xor(sum, 2);
      sum += __shfl_xor(sum, 4);
      if (r == 0) {
        float lg = sum + logb[v];
        lgcur[(size_t)b * VOC + v] = lg;
        if (lg > bm) { bm = lg; bmi = v; }
      }
    }
    if (r == 0) {
      ckvalcur[b * NCK + bid] = bm;
      ckidxcur[b * NCK + bid] = bmi;
    }
  } else if (bid < 512) {
    if (row >= 63) return;   // Vpre for row 64 never read
    int rowbase = (bid - 256) * 8;
    __shared__ float4 sr[8][D2/4];
    for (int idx = tid; idx < 8 * D2; idx += 256) {
      int rr = idx >> 7, k = idx & 127;
      ((float*)sr[rr])[k] = scur[(size_t)(rowbase + rr) * D2 + k];
    }
    __syncthreads();
    for (int gd = tid; gd < G5; gd += 256) {
      const float4* wrow = (const float4*)(Ws + (size_t)gd * (2*D2) + D2);
      float acc[8];
      #pragma unroll
      for (int rr = 0; rr < 8; ++rr) acc[rr] = 0.0f;
      for (int q = 0; q < D2/4; ++q) {
        float4 ww = wrow[q];
        #pragma unroll
        for (int rr = 0; rr < 8; ++rr) {
          float4 s4 = sr[rr][q];
          acc[rr] += ww.x*s4.x + ww.y*s4.y + ww.z*s4.z + ww.w*s4.w;
        }
      }
      #pragma unroll
      for (int rr = 0; rr < 8; ++rr) {
        size_t o = (size_t)(rowbase + rr) * G5 + gd;
        Vnxt[o] = Hx[o] + acc[rr];
      }
    }
  } else {
    if (row == 0) return;
    int b = bid - 512;
    __shared__ float red[256];
    red[tid] = ckvalprev[b * NCK + tid];
    __syncthreads();
    for (int off = 128; off > 0; off >>= 1) {
      if (tid < off) red[tid] = fmaxf(red[tid], red[tid + off]);
      __syncthreads();
    }
    float M = red[0];
    __syncthreads();
    const float* lg = lgprev + (size_t)b * VOC;
    float S = 0.0f;
    for (int k = 0; k < VPC; ++k) S += __expf(lg[tid + 256 * k] - M);
    red[tid] = S;
    __syncthreads();
    for (int off = 128; off > 0; off >>= 1) {
      if (tid < off) red[tid] += red[tid + off];
      __syncthreads();
    }
    float rinv = 1.0f / red[0];
    float* o = dout + ((size_t)(row - 1) * NB + b) * VOC;
    for (int k = 0; k < VPC; ++k) {
      int v = tid + 256 * k;
      o[v] = __expf(lg[v] - M) * rinv;
    }
  }
}

// ---------------------------------------------------------------------------
extern "C" void kernel_launch(void* const* d_in, const int* in_sizes, int n_in,
                              void* d_out, int out_size, void* d_ws, size_t ws_size,
                              hipStream_t stream)
{
  (void)in_sizes; (void)n_in; (void)out_size; (void)ws_size;
  const int*   x     = (const int*)d_in[0];
  const float* embed = (const float*)d_in[1];
  const float* Wihf  = (const float*)d_in[2];
  const float* Whhf  = (const float*)d_in[3];
  const float* bihf  = (const float*)d_in[4];
  const float* bhhf  = (const float*)d_in[5];
  const float* Wihb  = (const float*)d_in[6];
  const float* Whhb  = (const float*)d_in[7];
  const float* bihb  = (const float*)d_in[8];
  const float* bhhb  = (const float*)d_in[9];
  const float* Wx    = (const float*)d_in[10];
  const float* bx    = (const float*)d_in[11];
  const float* Ws    = (const float*)d_in[12];
  const float* bs    = (const float*)d_in[13];
  const float* logW  = (const float*)d_in[14];
  const float* logb  = (const float*)d_in[15];
  float* out = (float*)d_out;

  float* w    = (float*)d_ws;
  float* Xf   = w;                   // 64*32*512   = 1048576
  float* Xb   = Xf   + 1048576;      // 1048576
  float* henc = Xb   + 1048576;      // 64*32*256   = 524288
  float* Hx   = henc + 524288;       // 2048*640    = 1310720
  float* Vpre = Hx   + 1310720;      // 2 * 1310720
  float* SC   = Vpre + 2621440;      // [s0 c0 s1 c1], each 262144
  float* lg   = SC   + 1048576;      // 2 * 1024000
  float* ckv  = lg   + 2048000;      // 2 * 8192
  int*   cki  = (int*)(ckv + 16384); // 2 * 8192

  // zero the "previous row" state buffers (s1+c1, contiguous) for row 0
  hipMemsetAsync(SC + 524288, 0, (size_t)524288 * sizeof(float), stream);

  k_embed_encpre<<<256, 512, 0, stream>>>(x, embed, Wihf, bihf, bhhf,
                                          Wihb, bihb, bhhb, Xf, Xb);
  k_encoder<<<64, 512, 0, stream>>>(Xf, Xb, Whhf, Whhb, henc);
  k_hx<<<256, 640, 0, stream>>>(henc, Wx, bx, bs, Hx, Vpre /* Vpre[0] */);

  for (int i = 0; i <= 64; ++i) {
    int cur = i & 1, prv = (i + 1) & 1;   // (i-1)&1 == (i+1)&1
    float* scur  = SC + (size_t)cur * 524288;
    float* ccur  = scur + 262144;
    float* sprev = SC + (size_t)prv * 524288;
    float* cprev = sprev + 262144;
    if (i < 64) {
      k_row<<<32, 640, 0, stream>>>(i, embed, Wx, Ws,
          Vpre + (size_t)cur * 1310720, cprev, scur, ccur,
          ckv + (size_t)prv * 8192, cki + (size_t)prv * 8192);
    }
    k_fused<<<544, 256, 0, stream>>>(i, scur, logW, logb, Ws, Hx,
        Vpre + (size_t)prv * 1310720,
        lg + (size_t)cur * 1024000, ckv + (size_t)cur * 8192, cki + (size_t)cur * 8192,
        lg + (size_t)prv * 1024000, ckv + (size_t)prv * 8192,
        out);
  }
}

// Round 4
// 12866.692 us; speedup vs baseline: 1.1478x; 1.1478x over previous
//
#include <hip/hip_runtime.h>
#include <cstdint>
#include <cstddef>

#define LI 64
#define LO 64
#define NB 32
#define E  128
#define ENC 128
#define D2 128
#define VOC 32000
#define CIN 384   // 2*ENC + E
#define G5 640    // 5*D2
#define G4 512    // 4*ENC
#define NCK 256   // vocab chunks
#define VPC 125   // vocab per chunk

__device__ __forceinline__ float sigf(float x) { return 1.0f / (1.0f + __expf(-x)); }
__device__ __forceinline__ float tanhf_(float x) {
  float e = __expf(2.0f * x);
  return 1.0f - 2.0f / (e + 1.0f);
}

// raw barrier: wait LDS only (lgkmcnt), do NOT drain vmcnt (global stores /
// prefetches stay in flight across the barrier; kernel-end flush covers them)
#define BARL() __asm__ __volatile__("s_waitcnt lgkmcnt(0)\n\ts_barrier" ::: "memory")

// ---------------------------------------------------------------------------
// K1: embedding gather + encoder input precompute  Xf/Xb = emb@Wih.T + bih+bhh
// grid 256 = 64 t * 4 bgroups(8), block 512
__global__ __launch_bounds__(512) void k_embed_encpre(
    const int* __restrict__ x, const float* __restrict__ embed,
    const float* __restrict__ Wf, const float* __restrict__ bihf, const float* __restrict__ bhhf,
    const float* __restrict__ Wb, const float* __restrict__ bihb, const float* __restrict__ bhhb,
    float* __restrict__ Xf, float* __restrict__ Xb)
{
  int t = blockIdx.x >> 2, bg = (blockIdx.x & 3) * 8;
  __shared__ float4 embs[8][E/4];
  int tid = threadIdx.x;
  for (int idx = tid; idx < 8 * E; idx += 512) {
    int bb = idx >> 7, e = idx & 127;
    int tok = x[t * NB + bg + bb];
    ((float*)embs[bb])[e] = embed[(size_t)tok * E + e];
  }
  __syncthreads();
  int gd = tid;
  for (int dir = 0; dir < 2; ++dir) {
    const float4* wrow = (const float4*)((dir ? Wb : Wf) + (size_t)gd * E);
    float bias = dir ? (bihb[gd] + bhhb[gd]) : (bihf[gd] + bhhf[gd]);
    float acc[8];
    #pragma unroll
    for (int r = 0; r < 8; ++r) acc[r] = bias;
    for (int q = 0; q < E/4; ++q) {
      float4 w = wrow[q];
      #pragma unroll
      for (int r = 0; r < 8; ++r) {
        float4 e4 = embs[r][q];
        acc[r] += w.x*e4.x + w.y*e4.y + w.z*e4.z + w.w*e4.w;
      }
    }
    float* X = dir ? Xb : Xf;
    #pragma unroll
    for (int r = 0; r < 8; ++r)
      X[(size_t)(t * NB + bg + r) * G4 + gd] = acc[r];
  }
}

// ---------------------------------------------------------------------------
// K2: bidirectional encoder LSTM. grid 64 = 32 b * 2 dir, block 512.
// torch gate order (i,f,g,o). Whh row loaded through a volatile pointer:
// volatile loads execute exactly once, so the compiler cannot sink them into
// the step loop -> the 128 weight floats stay register-resident.
__global__ __launch_bounds__(512) void k_encoder(
    const float* __restrict__ Xf, const float* __restrict__ Xb,
    const float* __restrict__ Whhf, const float* __restrict__ Whhb,
    float* __restrict__ henc)
{
  int b = blockIdx.x >> 1, dir = blockIdx.x & 1;
  const float* X   = dir ? Xb   : Xf;
  const float* Whh = dir ? Whhb : Whhf;
  int tid = threadIdx.x;
  float4 w[ENC/4];
  {
    const volatile float* wrow = Whh + (size_t)tid * ENC;
    #pragma unroll
    for (int q = 0; q < ENC/4; ++q) {
      w[q].x = wrow[4*q + 0];
      w[q].y = wrow[4*q + 1];
      w[q].z = wrow[4*q + 2];
      w[q].w = wrow[4*q + 3];
    }
  }
  __shared__ float4 hb4[ENC/4];
  __shared__ float zb[G4];
  if (tid < ENC/4) hb4[tid] = make_float4(0.f, 0.f, 0.f, 0.f);
  float c = 0.0f;
  __syncthreads();
  for (int st = 0; st < LI; ++st) {
    int t = dir ? (LI - 1 - st) : st;
    float acc = X[(size_t)(t * NB + b) * G4 + tid];
    #pragma unroll
    for (int q = 0; q < ENC/4; ++q) {
      float4 h4 = hb4[q];
      float4 ww = w[q];
      acc += ww.x*h4.x + ww.y*h4.y + ww.z*h4.z + ww.w*h4.w;
    }
    zb[tid] = acc;
    __syncthreads();
    if (tid < ENC) {
      float zi = zb[tid], zf = zb[ENC + tid], zg = zb[2*ENC + tid], zo = zb[3*ENC + tid];
      c = sigf(zf) * c + sigf(zi) * tanhf_(zg);
      float h = sigf(zo) * tanhf_(c);
      ((float*)hb4)[tid] = h;
      henc[(size_t)(t * NB + b) * (2*ENC) + dir*ENC + tid] = h;
    }
    __syncthreads();
  }
}

// ---------------------------------------------------------------------------
// K3: Hx = henc @ Wx[:,128:384].T + bx + bs ; also seeds Vpre[0] (row 0: s_ver=0)
// grid 256 (8 rows each of 2048), block 640
__global__ __launch_bounds__(640) void k_hx(
    const float* __restrict__ henc, const float* __restrict__ Wx,
    const float* __restrict__ bx, const float* __restrict__ bs,
    float* __restrict__ Hx, float* __restrict__ Vpre0)
{
  int rowbase = blockIdx.x * 8;
  __shared__ float4 hh[8][(2*ENC)/4];
  int tid = threadIdx.x;
  for (int idx = tid; idx < 8 * 2 * ENC; idx += 640) {
    int rr = idx >> 8, k = idx & 255;
    ((float*)hh[rr])[k] = henc[(size_t)(rowbase + rr) * (2*ENC) + k];
  }
  __syncthreads();
  int gd = tid;
  const float4* wrow = (const float4*)(Wx + (size_t)gd * CIN + E);
  float bias = bx[gd] + bs[gd];
  float acc[8];
  #pragma unroll
  for (int r = 0; r < 8; ++r) acc[r] = bias;
  for (int q = 0; q < (2*ENC)/4; ++q) {
    float4 w = wrow[q];
    #pragma unroll
    for (int r = 0; r < 8; ++r) {
      float4 h4 = hh[r][q];
      acc[r] += w.x*h4.x + w.y*h4.y + w.z*h4.z + w.w*h4.w;
    }
  }
  #pragma unroll
  for (int r = 0; r < 8; ++r) {
    size_t o = (size_t)(rowbase + r) * G5 + gd;
    Hx[o] = acc[r];
    Vpre0[o] = acc[r];
  }
}

// ---------------------------------------------------------------------------
// K4 (per row): argmax(prev logits) -> y -> Yx, then 64 sequential 2D-LSTM cells.
// grid 32 (one WG per batch element), block 640 = 10 waves (3/3/2/2 per SIMD).
//
// __launch_bounds__(640, 3): 3 waves/SIMD -> VGPR cap 170.
// Ws row loaded through a VOLATILE pointer: volatile loads execute exactly
// once, so the compiler cannot sink/rematerialize them into the j-loop
// (round-1 counters: VGPR_Count=80 < 128 weight floats => weights were
// re-fetched from L2 every step, 327 KB/step/CU = the measured 2.6 us/step).
// 128 weight regs + ~25 working regs = ~155 <= 170: resident.
//
// s-broadcast: uniform-address LDS float4 reads (conflict-free broadcast) on
// the LDS pipe, overlapping the 128 FMAs on the VALU pipe.
//
// Gate phase on threads [128,256) (waves 2,3 -> the 2-wave SIMDs).
__global__ __launch_bounds__(640, 3) void k_row(
    int row,
    const float* __restrict__ embed, const float* __restrict__ Wx,
    const float* __restrict__ Ws,
    const float* __restrict__ Vpre,   // Vpre[row&1]: Hx + s_ver part + biases
    const float* __restrict__ cprev,  // c_row of previous row
    float* __restrict__ scur, float* __restrict__ ccur,
    const float* __restrict__ ckval, const int* __restrict__ ckidx)
{
  int b = blockIdx.x, tid = threadIdx.x;
  __shared__ float zb[G5];
  __shared__ float4 sb4[D2/4];
  __shared__ float ybuf[E];
  __shared__ int tokls;
  float yxr = 0.0f;
  if (row > 0) {
    if (tid < 64) {
      float bv = -3.4e38f; int bi = 0x7fffffff;
      #pragma unroll
      for (int cc = 0; cc < 4; ++cc) {
        int c = tid + 64 * cc;
        float v = ckval[b * NCK + c];
        int   id = ckidx[b * NCK + c];
        if (v > bv || (v == bv && id < bi)) { bv = v; bi = id; }
      }
      #pragma unroll
      for (int off = 1; off < 64; off <<= 1) {
        float ov = __shfl_xor(bv, off);
        int   oi = __shfl_xor(bi, off);
        if (ov > bv || (ov == bv && oi < bi)) { bv = ov; bi = oi; }
      }
      if (tid == 0) tokls = bi;
    }
    __syncthreads();
    int tok = tokls;
    if (tid < E) ybuf[tid] = embed[(size_t)tok * E + tid];
    __syncthreads();
    const float4* wy = (const float4*)(Wx + (size_t)tid * CIN);
    const float4* y4 = (const float4*)ybuf;
    float a = 0.0f;
    #pragma unroll
    for (int q = 0; q < E/4; ++q) {
      float4 w = wy[q], y = y4[q];
      a += w.x*y.x + w.y*y.y + w.z*y.z + w.w*y.w;
    }
    yxr = a;
  }
  // recurrent weights Ws[:,0:128] -> 128 VGPRs, forced resident via volatile
  float4 w4[D2/4];
  {
    const volatile float* wrow = Ws + (size_t)tid * (2*D2);
    #pragma unroll
    for (int q = 0; q < D2/4; ++q) {
      w4[q].x = wrow[4*q + 0];
      w4[q].y = wrow[4*q + 1];
      w4[q].z = wrow[4*q + 2];
      w4[q].w = wrow[4*q + 3];
    }
  }

  int gate = (tid >= D2 && tid < 2*D2);
  int d = tid - D2;
  if (tid < D2/4) sb4[tid] = make_float4(0.f, 0.f, 0.f, 0.f);
  float chor = 0.0f;
  float vnext = Vpre[(size_t)(0 * NB + b) * G5 + tid];
  float cvn = gate ? cprev[(size_t)(0 * NB + b) * D2 + d] : 0.0f;
  __syncthreads();

  for (int j = 0; j < LI; ++j) {
    float acc = yxr + vnext;
    if (j < LI - 1) vnext = Vpre[(size_t)((j + 1) * NB + b) * G5 + tid];
    #pragma unroll
    for (int q = 0; q < D2/4; ++q) {
      float4 s4 = sb4[q];
      float4 ww = w4[q];
      acc += ww.x*s4.x + ww.y*s4.y + ww.z*s4.z + ww.w*s4.w;
    }
    zb[tid] = acc;
    BARL();
    if (gate) {
      float zi = zb[d], zf = zb[D2 + d], zo = zb[2*D2 + d],
            zl = zb[3*D2 + d], zg = zb[4*D2 + d];
      float cv = cvn;
      if (j < LI - 1) cvn = cprev[(size_t)((j + 1) * NB + b) * D2 + d];
      float ii = sigf(zi), ff = sigf(zf), oo = sigf(zo), ll = sigf(zl);
      float gg = tanhf_(zg);
      float c = ff * (ll * chor + (1.0f - ll) * cv) + ii * gg;
      float s = oo * tanhf_(c);
      chor = c;
      ((float*)sb4)[d] = s;
      size_t o = (size_t)(j * NB + b) * D2 + d;
      ccur[o] = c;
      scur[o] = s;
    }
    BARL();
  }
}

// ---------------------------------------------------------------------------
// K5 (per row i, launched for i=0..64): three parts by blockIdx.
//  [0,256):  logits of row i (chunked) + per-chunk max/argmax
//  [256,512): Vpre[(i+1)&1] = Hx + s_row_i @ Ws[:,128:256].T
//  [512,544): softmax finalize + probs write of row i-1
__global__ __launch_bounds__(256) void k_fused(
    int row,
    const float* __restrict__ scur,
    const float* __restrict__ logW, const float* __restrict__ logb,
    const float* __restrict__ Ws, const float* __restrict__ Hx,
    float* __restrict__ Vnxt,
    float* __restrict__ lgcur, float* __restrict__ ckvalcur, int* __restrict__ ckidxcur,
    const float* __restrict__ lgprev, const float* __restrict__ ckvalprev,
    float* __restrict__ dout)
{
  int bid = blockIdx.x, tid = threadIdx.x;
  if (bid < 256) {
    if (row >= 64) return;
    int b = tid >> 3, r = tid & 7;
    const float4* sp = (const float4*)(scur + (size_t)(63 * NB + b) * D2 + r * 16);
    float4 s0 = sp[0], s1 = sp[1], s2 = sp[2], s3 = sp[3];
    float bm = -3.4e38f; int bmi = 0;
    int v0 = bid * VPC;
    for (int k = 0; k < VPC; ++k) {
      int v = v0 + k;
      const float4* lw = (const float4*)(logW + (size_t)v * D2 + r * 16);
      float4 a0 = lw[0], a1 = lw[1], a2 = lw[2], a3 = lw[3];
      float sum = a0.x*s0.x + a0.y*s0.y + a0.z*s0.z + a0.w*s0.w
                + a1.x*s1.x + a1.y*s1.y + a1.z*s1.z + a1.w*s1.w
                + a2.x*s2.x + a2.y*s2.y + a2.z*s2.z + a2.w*s2.w
                + a3.x*s3.x + a3.y*s3.y + a3.z*s3.z + a3.w*s3.w;
      sum += __shfl_xor(sum, 1);
      sum += __shfl_xor(sum, 2);
      sum += __shfl_xor(sum, 4);
      if (r == 0) {
        float lg = sum + logb[v];
        lgcur[(size_t)b * VOC + v] = lg;
        if (lg > bm) { bm = lg; bmi = v; }
      }
    }
    if (r == 0) {
      ckvalcur[b * NCK + bid] = bm;
      ckidxcur[b * NCK + bid] = bmi;
    }
  } else if (bid < 512) {
    if (row >= 63) return;   // Vpre for row 64 never read
    int rowbase = (bid - 256) * 8;
    __shared__ float4 sr[8][D2/4];
    for (int idx = tid; idx < 8 * D2; idx += 256) {
      int rr = idx >> 7, k = idx & 127;
      ((float*)sr[rr])[k] = scur[(size_t)(rowbase + rr) * D2 + k];
    }
    __syncthreads();
    for (int gd = tid; gd < G5; gd += 256) {
      const float4* wrow = (const float4*)(Ws + (size_t)gd * (2*D2) + D2);
      float acc[8];
      #pragma unroll
      for (int rr = 0; rr < 8; ++rr) acc[rr] = 0.0f;
      for (int q = 0; q < D2/4; ++q) {
        float4 ww = wrow[q];
        #pragma unroll
        for (int rr = 0; rr < 8; ++rr) {
          float4 s4 = sr[rr][q];
          acc[rr] += ww.x*s4.x + ww.y*s4.y + ww.z*s4.z + ww.w*s4.w;
        }
      }
      #pragma unroll
      for (int rr = 0; rr < 8; ++rr) {
        size_t o = (size_t)(rowbase + rr) * G5 + gd;
        Vnxt[o] = Hx[o] + acc[rr];
      }
    }
  } else {
    if (row == 0) return;
    int b = bid - 512;
    __shared__ float red[256];
    red[tid] = ckvalprev[b * NCK + tid];
    __syncthreads();
    for (int off = 128; off > 0; off >>= 1) {
      if (tid < off) red[tid] = fmaxf(red[tid], red[tid + off]);
      __syncthreads();
    }
    float M = red[0];
    __syncthreads();
    const float* lg = lgprev + (size_t)b * VOC;
    float S = 0.0f;
    for (int k = 0; k < VPC; ++k) S += __expf(lg[tid + 256 * k] - M);
    red[tid] = S;
    __syncthreads();
    for (int off = 128; off > 0; off >>= 1) {
      if (tid < off) red[tid] += red[tid + off];
      __syncthreads();
    }
    float rinv = 1.0f / red[0];
    float* o = dout + ((size_t)(row - 1) * NB + b) * VOC;
    for (int k = 0; k < VPC; ++k) {
      int v = tid + 256 * k;
      o[v] = __expf(lg[v] - M) * rinv;
    }
  }
}

// ---------------------------------------------------------------------------
extern "C" void kernel_launch(void* const* d_in, const int* in_sizes, int n_in,
                              void* d_out, int out_size, void* d_ws, size_t ws_size,
                              hipStream_t stream)
{
  (void)in_sizes; (void)n_in; (void)out_size; (void)ws_size;
  const int*   x     = (const int*)d_in[0];
  const float* embed = (const float*)d_in[1];
  const float* Wihf  = (const float*)d_in[2];
  const float* Whhf  = (const float*)d_in[3];
  const float* bihf  = (const float*)d_in[4];
  const float* bhhf  = (const float*)d_in[5];
  const float* Wihb  = (const float*)d_in[6];
  const float* Whhb  = (const float*)d_in[7];
  const float* bihb  = (const float*)d_in[8];
  const float* bhhb  = (const float*)d_in[9];
  const float* Wx    = (const float*)d_in[10];
  const float* bx    = (const float*)d_in[11];
  const float* Ws    = (const float*)d_in[12];
  const float* bs    = (const float*)d_in[13];
  const float* logW  = (const float*)d_in[14];
  const float* logb  = (const float*)d_in[15];
  float* out = (float*)d_out;

  float* w    = (float*)d_ws;
  float* Xf   = w;                   // 64*32*512   = 1048576
  float* Xb   = Xf   + 1048576;      // 1048576
  float* henc = Xb   + 1048576;      // 64*32*256   = 524288
  float* Hx   = henc + 524288;       // 2048*640    = 1310720
  float* Vpre = Hx   + 1310720;      // 2 * 1310720
  float* SC   = Vpre + 2621440;      // [s0 c0 s1 c1], each 262144
  float* lg   = SC   + 1048576;      // 2 * 1024000
  float* ckv  = lg   + 2048000;      // 2 * 8192
  int*   cki  = (int*)(ckv + 16384); // 2 * 8192

  // zero the "previous row" state buffers (s1+c1, contiguous) for row 0
  hipMemsetAsync(SC + 524288, 0, (size_t)524288 * sizeof(float), stream);

  k_embed_encpre<<<256, 512, 0, stream>>>(x, embed, Wihf, bihf, bhhf,
                                          Wihb, bihb, bhhb, Xf, Xb);
  k_encoder<<<64, 512, 0, stream>>>(Xf, Xb, Whhf, Whhb, henc);
  k_hx<<<256, 640, 0, stream>>>(henc, Wx, bx, bs, Hx, Vpre /* Vpre[0] */);

  for (int i = 0; i <= 64; ++i) {
    int cur = i & 1, prv = (i + 1) & 1;   // (i-1)&1 == (i+1)&1
    float* scur  = SC + (size_t)cur * 524288;
    float* ccur  = scur + 262144;
    float* sprev = SC + (size_t)prv * 524288;
    float* cprev = sprev + 262144;
    if (i < 64) {
      k_row<<<32, 640, 0, stream>>>(i, embed, Wx, Ws,
          Vpre + (size_t)cur * 1310720, cprev, scur, ccur,
          ckv + (size_t)prv * 8192, cki + (size_t)prv * 8192);
    }
    k_fused<<<544, 256, 0, stream>>>(i, scur, logW, logb, Ws, Hx,
        Vpre + (size_t)prv * 1310720,
        lg + (size_t)cur * 1024000, ckv + (size_t)cur * 8192, cki + (size_t)cur * 8192,
        lg + (size_t)prv * 1024000, ckv + (size_t)prv * 8192,
        out);
  }
}

// Round 5
// 10726.608 us; speedup vs baseline: 1.3768x; 1.1995x over previous
//
#include <hip/hip_runtime.h>
#include <cstdint>
#include <cstddef>

#define LI 64
#define LO 64
#define NB 32
#define E  128
#define ENC 128
#define D2 128
#define VOC 32000
#define CIN 384   // 2*ENC + E
#define G5 640    // 5*D2
#define G4 512    // 4*ENC
#define NCK 256   // vocab chunks
#define VPC 125   // vocab per chunk

__device__ __forceinline__ float sigf(float x) { return 1.0f / (1.0f + __expf(-x)); }
__device__ __forceinline__ float tanhf_(float x) {
  float e = __expf(2.0f * x);
  return 1.0f - 2.0f / (e + 1.0f);
}

// raw barrier: wait LDS only (lgkmcnt), do NOT drain vmcnt (global stores /
// prefetches stay in flight across the barrier; data deps still get their own
// compiler-inserted vmcnt waits; kernel-end flush covers store visibility)
#define BARL() __asm__ __volatile__("s_waitcnt lgkmcnt(0)\n\ts_barrier" ::: "memory")

// ---------------------------------------------------------------------------
// K1: embedding gather + encoder input precompute  Xf/Xb = emb@Wih.T + bih+bhh
// grid 256 = 64 t * 4 bgroups(8), block 512
__global__ __launch_bounds__(512) void k_embed_encpre(
    const int* __restrict__ x, const float* __restrict__ embed,
    const float* __restrict__ Wf, const float* __restrict__ bihf, const float* __restrict__ bhhf,
    const float* __restrict__ Wb, const float* __restrict__ bihb, const float* __restrict__ bhhb,
    float* __restrict__ Xf, float* __restrict__ Xb)
{
  int t = blockIdx.x >> 2, bg = (blockIdx.x & 3) * 8;
  __shared__ float4 embs[8][E/4];
  int tid = threadIdx.x;
  for (int idx = tid; idx < 8 * E; idx += 512) {
    int bb = idx >> 7, e = idx & 127;
    int tok = x[t * NB + bg + bb];
    ((float*)embs[bb])[e] = embed[(size_t)tok * E + e];
  }
  __syncthreads();
  int gd = tid;
  for (int dir = 0; dir < 2; ++dir) {
    const float4* wrow = (const float4*)((dir ? Wb : Wf) + (size_t)gd * E);
    float bias = dir ? (bihb[gd] + bhhb[gd]) : (bihf[gd] + bhhf[gd]);
    float acc[8];
    #pragma unroll
    for (int r = 0; r < 8; ++r) acc[r] = bias;
    for (int q = 0; q < E/4; ++q) {
      float4 w = wrow[q];
      #pragma unroll
      for (int r = 0; r < 8; ++r) {
        float4 e4 = embs[r][q];
        acc[r] += w.x*e4.x + w.y*e4.y + w.z*e4.z + w.w*e4.w;
      }
    }
    float* X = dir ? Xb : Xf;
    #pragma unroll
    for (int r = 0; r < 8; ++r)
      X[(size_t)(t * NB + bg + r) * G4 + gd] = acc[r];
  }
}

// ---------------------------------------------------------------------------
// K2: bidirectional encoder LSTM. grid 64 = 32 b * 2 dir, block 512.
// torch gate order (i,f,g,o).  (byte-exact r0 version — proven)
__global__ __launch_bounds__(512) void k_encoder(
    const float* __restrict__ Xf, const float* __restrict__ Xb,
    const float* __restrict__ Whhf, const float* __restrict__ Whhb,
    float* __restrict__ henc)
{
  int b = blockIdx.x >> 1, dir = blockIdx.x & 1;
  const float* X   = dir ? Xb   : Xf;
  const float* Whh = dir ? Whhb : Whhf;
  int tid = threadIdx.x;
  float4 w[ENC/4];
  {
    const float4* wrow = (const float4*)(Whh + (size_t)tid * ENC);
    #pragma unroll
    for (int q = 0; q < ENC/4; ++q) w[q] = wrow[q];
  }
  __shared__ float4 hb4[ENC/4];
  __shared__ float zb[G4];
  if (tid < ENC/4) hb4[tid] = make_float4(0.f, 0.f, 0.f, 0.f);
  float c = 0.0f;
  __syncthreads();
  for (int st = 0; st < LI; ++st) {
    int t = dir ? (LI - 1 - st) : st;
    float acc = X[(size_t)(t * NB + b) * G4 + tid];
    #pragma unroll
    for (int q = 0; q < ENC/4; ++q) {
      float4 h4 = hb4[q];
      float4 ww = w[q];
      acc += ww.x*h4.x + ww.y*h4.y + ww.z*h4.z + ww.w*h4.w;
    }
    zb[tid] = acc;
    __syncthreads();
    if (tid < ENC) {
      float zi = zb[tid], zf = zb[ENC + tid], zg = zb[2*ENC + tid], zo = zb[3*ENC + tid];
      c = sigf(zf) * c + sigf(zi) * tanhf_(zg);
      float h = sigf(zo) * tanhf_(c);
      ((float*)hb4)[tid] = h;
      henc[(size_t)(t * NB + b) * (2*ENC) + dir*ENC + tid] = h;
    }
    __syncthreads();
  }
}

// ---------------------------------------------------------------------------
// K3: Hx = henc @ Wx[:,128:384].T + bx + bs ; also seeds Vpre[0] (row 0: s_ver=0)
// grid 256 (8 rows each of 2048), block 640
__global__ __launch_bounds__(640) void k_hx(
    const float* __restrict__ henc, const float* __restrict__ Wx,
    const float* __restrict__ bx, const float* __restrict__ bs,
    float* __restrict__ Hx, float* __restrict__ Vpre0)
{
  int rowbase = blockIdx.x * 8;
  __shared__ float4 hh[8][(2*ENC)/4];
  int tid = threadIdx.x;
  for (int idx = tid; idx < 8 * 2 * ENC; idx += 640) {
    int rr = idx >> 8, k = idx & 255;
    ((float*)hh[rr])[k] = henc[(size_t)(rowbase + rr) * (2*ENC) + k];
  }
  __syncthreads();
  int gd = tid;
  const float4* wrow = (const float4*)(Wx + (size_t)gd * CIN + E);
  float bias = bx[gd] + bs[gd];
  float acc[8];
  #pragma unroll
  for (int r = 0; r < 8; ++r) acc[r] = bias;
  for (int q = 0; q < (2*ENC)/4; ++q) {
    float4 w = wrow[q];
    #pragma unroll
    for (int r = 0; r < 8; ++r) {
      float4 h4 = hh[r][q];
      acc[r] += w.x*h4.x + w.y*h4.y + w.z*h4.z + w.w*h4.w;
    }
  }
  #pragma unroll
  for (int r = 0; r < 8; ++r) {
    size_t o = (size_t)(rowbase + r) * G5 + gd;
    Hx[o] = acc[r];
    Vpre0[o] = acc[r];
  }
}

// ---------------------------------------------------------------------------
// K4 (per row): argmax(prev logits) -> y -> Yx, then 64 sequential 2D-LSTM cells.
// grid 32 (one WG per batch element), block 640 = 10 waves.
//
// Step structure (3 phases, 3 lgkm-barriers):
//  D:   half-K paired dot. Thread t<320 owns k in [0,64) for gate rows {t, t+320};
//       thread t>=320 owns k in [64,128) for the same pair. Each thread reads
//       only HALF of s (16 uniform b128 broadcasts vs 32) -> LDS return traffic
//       halves (r0's unhidden ~1280 cy/step -> ~640). Weights stream from L2
//       (shared by all 32 blocks; overlaps with VALU — proven by r0/r4 data).
//  Act: all 640 threads apply their own gate activation in-register
//       (type = tid>>7: i,f,o,l sigmoid; g tanh), write ab[tid]. Replaces the
//       serial 5-transcendental chain on 2 waves.
//  C:   128 threads combine: c = f*(l*c_hor + (1-l)*c_ver) + i*g, s = o*tanh(c).
__global__ __launch_bounds__(640) void k_row(
    int row,
    const float* __restrict__ embed, const float* __restrict__ Wx,
    const float* __restrict__ Ws,
    const float* __restrict__ Vpre,   // Vpre[row&1]: Hx + s_ver part + biases
    const float* __restrict__ cprev,  // c_row of previous row
    float* __restrict__ scur, float* __restrict__ ccur,
    const float* __restrict__ ckval, const int* __restrict__ ckidx)
{
  int b = blockIdx.x, tid = threadIdx.x;
  __shared__ float pbuf[2 * G5];    // [half][gate] weight-dot partials
  __shared__ float ab[G5];          // activations
  __shared__ float4 sb4[D2/4];      // s broadcast buffer
  __shared__ float ybuf[E];
  __shared__ int tokls;
  float yxr = 0.0f;
  if (row > 0) {
    if (tid < 64) {
      float bv = -3.4e38f; int bi = 0x7fffffff;
      #pragma unroll
      for (int cc = 0; cc < 4; ++cc) {
        int c = tid + 64 * cc;
        float v = ckval[b * NCK + c];
        int   id = ckidx[b * NCK + c];
        if (v > bv || (v == bv && id < bi)) { bv = v; bi = id; }
      }
      #pragma unroll
      for (int off = 1; off < 64; off <<= 1) {
        float ov = __shfl_xor(bv, off);
        int   oi = __shfl_xor(bi, off);
        if (ov > bv || (ov == bv && oi < bi)) { bv = ov; bi = oi; }
      }
      if (tid == 0) tokls = bi;
    }
    __syncthreads();
    int tok = tokls;
    if (tid < E) ybuf[tid] = embed[(size_t)tok * E + tid];
    __syncthreads();
    const float4* wy = (const float4*)(Wx + (size_t)tid * CIN);
    const float4* y4 = (const float4*)ybuf;
    float a = 0.0f;
    #pragma unroll
    for (int q = 0; q < E/4; ++q) {
      float4 w = wy[q], y = y4[q];
      a += w.x*y.x + w.y*y.y + w.z*y.z + w.w*y.w;
    }
    yxr = a;   // Yx contribution for gate row `tid`
  }

  // half-K pairing: thread t covers k-range [h*64, h*64+64) of gate rows g0,g1
  int h  = (tid >= 320) ? 1 : 0;          // wave-uniform (waves 0-4: h=0, 5-9: h=1)
  int g0 = tid - h * 320;                 // in [0,320)
  int g1 = g0 + 320;
  const float4* wrowA = (const float4*)(Ws + (size_t)g0 * (2*D2) + h*64);
  const float4* wrowB = (const float4*)(Ws + (size_t)g1 * (2*D2) + h*64);

  int gate = (tid < D2);
  int d = tid;
  if (tid < D2/4) sb4[tid] = make_float4(0.f, 0.f, 0.f, 0.f);
  float chor = 0.0f;
  float vcur = Vpre[(size_t)(0 * NB + b) * G5 + tid];
  float cvn = gate ? cprev[(size_t)(0 * NB + b) * D2 + d] : 0.0f;
  __syncthreads();

  for (int j = 0; j < LI; ++j) {
    // --- D: paired half-dot ---
    float accA = 0.0f, accB = 0.0f;
    #pragma unroll
    for (int q = 0; q < 16; ++q) {
      float4 s4 = sb4[h * 16 + q];       // uniform broadcast, half of s
      float4 wa = wrowA[q];
      float4 wb = wrowB[q];
      accA += wa.x*s4.x + wa.y*s4.y + wa.z*s4.z + wa.w*s4.w;
      accB += wb.x*s4.x + wb.y*s4.y + wb.z*s4.z + wb.w*s4.w;
    }
    pbuf[h * G5 + g0] = accA;
    pbuf[h * G5 + g1] = accB;
    float vnxt = (j < LI - 1) ? Vpre[(size_t)((j + 1) * NB + b) * G5 + tid] : 0.0f;
    BARL();
    // --- Act: per-gate activation, in-register z ---
    float z = yxr + vcur + pbuf[tid] + pbuf[G5 + tid];
    float act = (tid >= 4 * D2) ? tanhf_(z) : sigf(z);
    ab[tid] = act;
    BARL();
    // --- C: combine on 128 threads ---
    if (gate) {
      float ii = ab[d], ff = ab[D2 + d], oo = ab[2*D2 + d],
            ll = ab[3*D2 + d], gg = ab[4*D2 + d];
      float cv = cvn;
      if (j < LI - 1) cvn = cprev[(size_t)((j + 1) * NB + b) * D2 + d];
      float c = ff * (ll * chor + (1.0f - ll) * cv) + ii * gg;
      float s = oo * tanhf_(c);
      chor = c;
      ((float*)sb4)[d] = s;
      size_t o = (size_t)(j * NB + b) * D2 + d;
      ccur[o] = c;
      scur[o] = s;
    }
    vcur = vnxt;
    BARL();
  }
}

// ---------------------------------------------------------------------------
// K5 (per row i, launched for i=0..64): three parts by blockIdx.
//  [0,256):  logits of row i (chunked) + per-chunk max/argmax
//  [256,512): Vpre[(i+1)&1] = Hx + s_row_i @ Ws[:,128:256].T
//  [512,544): softmax finalize + probs write of row i-1
__global__ __launch_bounds__(256) void k_fused(
    int row,
    const float* __restrict__ scur,
    const float* __restrict__ logW, const float* __restrict__ logb,
    const float* __restrict__ Ws, const float* __restrict__ Hx,
    float* __restrict__ Vnxt,
    float* __restrict__ lgcur, float* __restrict__ ckvalcur, int* __restrict__ ckidxcur,
    const float* __restrict__ lgprev, const float* __restrict__ ckvalprev,
    float* __restrict__ dout)
{
  int bid = blockIdx.x, tid = threadIdx.x;
  if (bid < 256) {
    if (row >= 64) return;
    int b = tid >> 3, r = tid & 7;
    const float4* sp = (const float4*)(scur + (size_t)(63 * NB + b) * D2 + r * 16);
    float4 s0 = sp[0], s1 = sp[1], s2 = sp[2], s3 = sp[3];
    float bm = -3.4e38f; int bmi = 0;
    int v0 = bid * VPC;
    for (int k = 0; k < VPC; ++k) {
      int v = v0 + k;
      const float4* lw = (const float4*)(logW + (size_t)v * D2 + r * 16);
      float4 a0 = lw[0], a1 = lw[1], a2 = lw[2], a3 = lw[3];
      float sum = a0.x*s0.x + a0.y*s0.y + a0.z*s0.z + a0.w*s0.w
                + a1.x*s1.x + a1.y*s1.y + a1.z*s1.z + a1.w*s1.w
                + a2.x*s2.x + a2.y*s2.y + a2.z*s2.z + a2.w*s2.w
                + a3.x*s3.x + a3.y*s3.y + a3.z*s3.z + a3.w*s3.w;
      sum += __shfl_xor(sum, 1);
      sum += __shfl_xor(sum, 2);
      sum += __shfl_xor(sum, 4);
      if (r == 0) {
        float lg = sum + logb[v];
        lgcur[(size_t)b * VOC + v] = lg;
        if (lg > bm) { bm = lg; bmi = v; }
      }
    }
    if (r == 0) {
      ckvalcur[b * NCK + bid] = bm;
      ckidxcur[b * NCK + bid] = bmi;
    }
  } else if (bid < 512) {
    if (row >= 63) return;   // Vpre for row 64 never read
    int rowbase = (bid - 256) * 8;
    __shared__ float4 sr[8][D2/4];
    for (int idx = tid; idx < 8 * D2; idx += 256) {
      int rr = idx >> 7, k = idx & 127;
      ((float*)sr[rr])[k] = scur[(size_t)(rowbase + rr) * D2 + k];
    }
    __syncthreads();
    for (int gd = tid; gd < G5; gd += 256) {
      const float4* wrow = (const float4*)(Ws + (size_t)gd * (2*D2) + D2);
      float acc[8];
      #pragma unroll
      for (int rr = 0; rr < 8; ++rr) acc[rr] = 0.0f;
      for (int q = 0; q < D2/4; ++q) {
        float4 ww = wrow[q];
        #pragma unroll
        for (int rr = 0; rr < 8; ++rr) {
          float4 s4 = sr[rr][q];
          acc[rr] += ww.x*s4.x + ww.y*s4.y + ww.z*s4.z + ww.w*s4.w;
        }
      }
      #pragma unroll
      for (int rr = 0; rr < 8; ++rr) {
        size_t o = (size_t)(rowbase + rr) * G5 + gd;
        Vnxt[o] = Hx[o] + acc[rr];
      }
    }
  } else {
    if (row == 0) return;
    int b = bid - 512;
    __shared__ float red[256];
    red[tid] = ckvalprev[b * NCK + tid];
    __syncthreads();
    for (int off = 128; off > 0; off >>= 1) {
      if (tid < off) red[tid] = fmaxf(red[tid], red[tid + off]);
      __syncthreads();
    }
    float M = red[0];
    __syncthreads();
    const float* lg = lgprev + (size_t)b * VOC;
    float S = 0.0f;
    for (int k = 0; k < VPC; ++k) S += __expf(lg[tid + 256 * k] - M);
    red[tid] = S;
    __syncthreads();
    for (int off = 128; off > 0; off >>= 1) {
      if (tid < off) red[tid] += red[tid + off];
      __syncthreads();
    }
    float rinv = 1.0f / red[0];
    float* o = dout + ((size_t)(row - 1) * NB + b) * VOC;
    for (int k = 0; k < VPC; ++k) {
      int v = tid + 256 * k;
      o[v] = __expf(lg[v] - M) * rinv;
    }
  }
}

// ---------------------------------------------------------------------------
extern "C" void kernel_launch(void* const* d_in, const int* in_sizes, int n_in,
                              void* d_out, int out_size, void* d_ws, size_t ws_size,
                              hipStream_t stream)
{
  (void)in_sizes; (void)n_in; (void)out_size; (void)ws_size;
  const int*   x     = (const int*)d_in[0];
  const float* embed = (const float*)d_in[1];
  const float* Wihf  = (const float*)d_in[2];
  const float* Whhf  = (const float*)d_in[3];
  const float* bihf  = (const float*)d_in[4];
  const float* bhhf  = (const float*)d_in[5];
  const float* Wihb  = (const float*)d_in[6];
  const float* Whhb  = (const float*)d_in[7];
  const float* bihb  = (const float*)d_in[8];
  const float* bhhb  = (const float*)d_in[9];
  const float* Wx    = (const float*)d_in[10];
  const float* bx    = (const float*)d_in[11];
  const float* Ws    = (const float*)d_in[12];
  const float* bs    = (const float*)d_in[13];
  const float* logW  = (const float*)d_in[14];
  const float* logb  = (const float*)d_in[15];
  float* out = (float*)d_out;

  float* w    = (float*)d_ws;
  float* Xf   = w;                   // 64*32*512   = 1048576
  float* Xb   = Xf   + 1048576;      // 1048576
  float* henc = Xb   + 1048576;      // 64*32*256   = 524288
  float* Hx   = henc + 524288;       // 2048*640    = 1310720
  float* Vpre = Hx   + 1310720;      // 2 * 1310720
  float* SC   = Vpre + 2621440;      // [s0 c0 s1 c1], each 262144
  float* lg   = SC   + 1048576;      // 2 * 1024000
  float* ckv  = lg   + 2048000;      // 2 * 8192
  int*   cki  = (int*)(ckv + 16384); // 2 * 8192

  // zero the "previous row" state buffers (s1+c1, contiguous) for row 0
  hipMemsetAsync(SC + 524288, 0, (size_t)524288 * sizeof(float), stream);

  k_embed_encpre<<<256, 512, 0, stream>>>(x, embed, Wihf, bihf, bhhf,
                                          Wihb, bihb, bhhb, Xf, Xb);
  k_encoder<<<64, 512, 0, stream>>>(Xf, Xb, Whhf, Whhb, henc);
  k_hx<<<256, 640, 0, stream>>>(henc, Wx, bx, bs, Hx, Vpre /* Vpre[0] */);

  for (int i = 0; i <= 64; ++i) {
    int cur = i & 1, prv = (i + 1) & 1;   // (i-1)&1 == (i+1)&1
    float* scur  = SC + (size_t)cur * 524288;
    float* ccur  = scur + 262144;
    float* sprev = SC + (size_t)prv * 524288;
    float* cprev = sprev + 262144;
    if (i < 64) {
      k_row<<<32, 640, 0, stream>>>(i, embed, Wx, Ws,
          Vpre + (size_t)cur * 1310720, cprev, scur, ccur,
          ckv + (size_t)prv * 8192, cki + (size_t)prv * 8192);
    }
    k_fused<<<544, 256, 0, stream>>>(i, scur, logW, logb, Ws, Hx,
        Vpre + (size_t)prv * 1310720,
        lg + (size_t)cur * 1024000, ckv + (size_t)cur * 8192, cki + (size_t)cur * 8192,
        lg + (size_t)prv * 1024000, ckv + (size_t)prv * 8192,
        out);
  }
}